// Round 2
// baseline (1071.419 us; speedup 1.0000x reference)
//
#include <hip/hip_runtime.h>
#include <cstdint>

#define NTOK 2048
#define DMODEL 1024
#define NHEADS 16
#define HD 64
#define BATCH 2
#define EPSF 1e-10f
#define EPSD 1e-10

typedef __attribute__((ext_vector_type(8))) short bf16x8;
typedef __attribute__((ext_vector_type(4))) float f32x4;

__device__ __forceinline__ unsigned short f2bf(float f){
  union { float f; unsigned int u; } c; c.f = f;
  unsigned int u = c.u;
  unsigned int r = (u + 0x7FFFu + ((u >> 16) & 1u)) >> 16;
  return (unsigned short)r;
}

__device__ __forceinline__ void async16(const unsigned short* g, unsigned short* lds_base){
  __builtin_amdgcn_global_load_lds((const __attribute__((address_space(1))) unsigned int*)g,
                                   (__attribute__((address_space(3))) unsigned int*)lds_base,
                                   16, 0, 0);
}

// C[m,n] = sum_k A[m,k] * B[n,k]  (both K-major bf16), 256 threads, waves 2x2.
template<int BM, int BN>
__device__ __forceinline__ void gemm_bt_core(
    const unsigned short* A, int lda,
    const unsigned short* B, int ldb,
    int K,
    f32x4 (&acc)[BM/32][BN/32],
    unsigned short* ldsA, unsigned short* ldsB)
{
  constexpr int TM = BM/32, TN = BN/32;
  const int tid  = threadIdx.x;
  const int lane = tid & 63;
  const int wave = tid >> 6;
  const int wm = wave >> 1, wn = wave & 1;
  const int fr = lane & 15;
  const int fk = (lane >> 4) << 3;
  const int sr = lane >> 2;            // staging: row-in-chunk
  const int sk = (lane & 3) << 3;      // staging: k offset (elements)

  for (int k0 = 0; k0 < K; k0 += 32){
    #pragma unroll
    for (int c = 0; c < BM/64; c++){
      int ch = c*4 + wave;             // chunk = 16 rows x 32 cols
      async16(A + (long)(ch*16 + sr)*lda + (k0 + sk), ldsA + ch*512);
    }
    #pragma unroll
    for (int c = 0; c < BN/64; c++){
      int ch = c*4 + wave;
      async16(B + (long)(ch*16 + sr)*ldb + (k0 + sk), ldsB + ch*512);
    }
    __syncthreads();
    bf16x8 af[TM], bf[TN];
    #pragma unroll
    for (int i=0;i<TM;i++)
      af[i] = *(const bf16x8*)(ldsA + ((wm*TM*16) + i*16 + fr)*32 + fk);
    #pragma unroll
    for (int j=0;j<TN;j++)
      bf[j] = *(const bf16x8*)(ldsB + ((wn*TN*16) + j*16 + fr)*32 + fk);
    #pragma unroll
    for (int i=0;i<TM;i++)
      #pragma unroll
      for (int j=0;j<TN;j++)
        acc[i][j] = __builtin_amdgcn_mfma_f32_16x16x32_bf16(af[i], bf[j], acc[i][j], 0, 0, 0);
    __syncthreads();
  }
}

__device__ __forceinline__ float wred_max(float x){
  for(int o=32;o;o>>=1) x=fmaxf(x,__shfl_xor(x,o)); return x;
}
__device__ __forceinline__ float wred_sum(float x){
  for(int o=32;o;o>>=1) x+=__shfl_xor(x,o); return x;
}
__device__ __forceinline__ double wred_sumd(double x){
  for(int o=32;o;o>>=1) x+=__shfl_xor(x,o); return x;
}

// ---------------- kernels ----------------

__global__ void f2b_kernel(const float* __restrict__ in, unsigned short* __restrict__ out, int n){
  int i = blockIdx.x*256 + threadIdx.x;
  if (i < n) out[i] = f2bf(in[i]);
}

__global__ void init_kernel(float* __restrict__ fz, long nf, double* __restrict__ dz){
  long idx = (long)blockIdx.x*256 + threadIdx.x;
  if (idx < nf) fz[idx] = 0.0f;
  else {
    long d = idx - nf;
    if (d < 8192) dz[d] = 1.0;                 // u, v
    else if (d < 8192 + 40960) dz[d] = 0.0;    // R
  }
}

__global__ __launch_bounds__(256) void qkv_kernel(
    const unsigned short* __restrict__ xb,
    const unsigned short* __restrict__ Wqb, const float* __restrict__ bq,
    const unsigned short* __restrict__ Wkb, const float* __restrict__ bk,
    const unsigned short* __restrict__ Wvb, const float* __restrict__ bv,
    unsigned short* __restrict__ Qb, unsigned short* __restrict__ Kb,
    unsigned short* __restrict__ Vb)
{
  __shared__ unsigned short lds[(128+128)*32];
  int sel = blockIdx.y >> 3;
  int n0 = (blockIdx.y & 7) * 128;
  int m0 = blockIdx.x * 128;
  const unsigned short* W = sel==0 ? Wqb : (sel==1 ? Wkb : Wvb);
  const float* bias       = sel==0 ? bq  : (sel==1 ? bk  : bv);
  unsigned short* out     = sel==0 ? Qb  : (sel==1 ? Kb  : Vb);
  f32x4 acc[4][4];
  f32x4 z = {0.f,0.f,0.f,0.f};
  for (int i=0;i<4;i++) for(int j=0;j<4;j++) acc[i][j] = z;
  gemm_bt_core<128,128>(xb + (long)m0*DMODEL, DMODEL, W + (long)n0*DMODEL, DMODEL,
                        DMODEL, acc, lds, lds + 128*32);
  int lane = threadIdx.x & 63, wave = threadIdx.x >> 6;
  int wm = wave>>1, wn = wave&1;
  int cr = (lane>>4)<<2, cc = lane & 15;
  for (int i=0;i<4;i++) for(int j=0;j<4;j++) for(int r=0;r<4;r++){
    int row = m0 + wm*64 + i*16 + cr + r;
    int col = n0 + wn*64 + j*16 + cc;
    out[(long)row*DMODEL + col] = f2bf(acc[i][j][r] + bias[col]);
  }
}

__global__ void vtrans_kernel(const unsigned short* __restrict__ Vb,
                              unsigned short* __restrict__ Vt)
{
  __shared__ unsigned short t[32][33];
  int b = blockIdx.z, i0 = blockIdx.x*32, e0 = blockIdx.y*32;
  int tx = threadIdx.x, ty = threadIdx.y;
  for (int r=0;r<32;r+=8) t[ty+r][tx] = Vb[((long)b*NTOK + i0+ty+r)*DMODEL + e0+tx];
  __syncthreads();
  for (int r=0;r<32;r+=8) Vt[((long)b*DMODEL + e0+ty+r)*NTOK + i0+tx] = t[tx][ty+r];
}

__global__ __launch_bounds__(256) void scores_kernel(
    const unsigned short* __restrict__ Qb, const unsigned short* __restrict__ Kb,
    const int* __restrict__ perm, const float* __restrict__ pscale,
    float* __restrict__ S, int h)
{
  __shared__ unsigned short lds[(128+128)*32];
  int b = blockIdx.z;
  int m0 = blockIdx.x*128, n0 = blockIdx.y*128;
  const unsigned short* A = Qb + ((long)b*NTOK)*DMODEL + h*HD;
  const unsigned short* B = Kb + ((long)b*NTOK)*DMODEL + h*HD;
  f32x4 acc[4][4];
  f32x4 z = {0.f,0.f,0.f,0.f};
  for (int i=0;i<4;i++) for(int j=0;j<4;j++) acc[i][j] = z;
  gemm_bt_core<128,128>(A + (long)m0*DMODEL, DMODEL, B + (long)n0*DMODEL, DMODEL,
                        HD, acc, lds, lds + 128*32);
  float asc = fabsf(pscale[h]);
  const int* pb = perm + b*NTOK;
  float* Sb = S + (long)b*NTOK*NTOK;
  int lane = threadIdx.x & 63, wave = threadIdx.x >> 6;
  int wm = wave>>1, wn = wave&1;
  int cr = (lane>>4)<<2, cc = lane & 15;
  for (int i=0;i<4;i++) for(int j=0;j<4;j++) for(int r=0;r<4;r++){
    int row = m0 + wm*64 + i*16 + cr + r;
    int col = n0 + wn*64 + j*16 + cc;
    float pi = (float)pb[row], pj = (float)pb[col];
    Sb[(long)row*NTOK + col] = acc[i][j][r]*0.125f - fabsf(pi - pj)*asc;
  }
}

__global__ __launch_bounds__(256) void softmax_kernel(
    const float* __restrict__ S, unsigned short* __restrict__ Abuf,
    float* __restrict__ avg, float* __restrict__ entsum)
{
  __shared__ float red[4];
  int i = blockIdx.x, b = blockIdx.y, tid = threadIdx.x;
  const float* row = S + ((long)b*NTOK + i)*NTOK;
  float v[8];
  #pragma unroll
  for (int k=0;k<8;k++) v[k] = row[k*256 + tid];
  float m = -3.0e38f;
  #pragma unroll
  for (int k=0;k<8;k++) m = fmaxf(m, v[k]);
  m = wred_max(m);
  if ((tid&63)==0) red[tid>>6] = m;
  __syncthreads();
  m = fmaxf(fmaxf(red[0],red[1]), fmaxf(red[2],red[3]));
  __syncthreads();
  float e[8]; float s = 0.f;
  #pragma unroll
  for (int k=0;k<8;k++){ e[k] = expf(v[k]-m); s += e[k]; }
  s = wred_sum(s);
  if ((tid&63)==0) red[tid>>6] = s;
  __syncthreads();
  s = red[0]+red[1]+red[2]+red[3];
  __syncthreads();
  float inv = 1.0f/s;
  unsigned short* Ar = Abuf + ((long)b*NTOK + i)*NTOK;
  float* avr = avg + ((long)b*NTOK + i)*NTOK;
  float ep = 0.f;
  #pragma unroll
  for (int k=0;k<8;k++){
    int j = k*256+tid;
    float a = e[k]*inv;
    Ar[j] = f2bf(a);
    avr[j] += a * 0.0625f;
    ep += a * logf(a + EPSF);
  }
  ep = wred_sum(ep);
  if ((tid&63)==0) red[tid>>6] = ep;
  __syncthreads();
  if (tid==0) entsum[b*NTOK+i] += red[0]+red[1]+red[2]+red[3];
}

__global__ __launch_bounds__(256) void av_kernel(
    const unsigned short* __restrict__ Abuf, const unsigned short* __restrict__ Vt,
    float* __restrict__ Of32, int h)
{
  __shared__ unsigned short lds[(128+64)*32];
  int b = blockIdx.z, m0 = blockIdx.x*128, kc = blockIdx.y;
  const unsigned short* A = Abuf + (long)b*NTOK*NTOK + (long)m0*NTOK + kc*256;
  const unsigned short* B = Vt + ((long)b*DMODEL + h*HD)*NTOK + kc*256;
  f32x4 acc[4][2];
  f32x4 z = {0.f,0.f,0.f,0.f};
  for (int i=0;i<4;i++) for(int j=0;j<2;j++) acc[i][j] = z;
  gemm_bt_core<128,64>(A, NTOK, B, NTOK, 256, acc, lds, lds + 128*32);
  int lane = threadIdx.x & 63, wave = threadIdx.x >> 6;
  int wm = wave>>1, wn = wave&1;
  int cr = (lane>>4)<<2, cc = lane & 15;
  for (int i=0;i<4;i++) for(int j=0;j<2;j++) for(int r=0;r<4;r++){
    int row = m0 + wm*64 + i*16 + cr + r;
    int col = wn*32 + j*16 + cc;
    atomicAdd(&Of32[((long)b*NTOK + row)*DMODEL + h*HD + col], acc[i][j][r]);
  }
}

__global__ void pow_kernel(float* __restrict__ avg, long n){
  long idx = (long)blockIdx.x*256 + threadIdx.x;
  for (long i = idx; i < n; i += (long)gridDim.x*256){
    float xv = avg[i];
    avg[i] = expf(logf(xv + EPSF) * 10.0f);
  }
}

__global__ __launch_bounds__(256) void sink_row(const float* __restrict__ P,
    const double* __restrict__ v, double* __restrict__ u)
{
  __shared__ double red[4];
  int i = blockIdx.x, b = blockIdx.y, tid = threadIdx.x;
  const float* row = P + ((long)b*NTOK+i)*NTOK;
  const double* vb = v + b*NTOK;
  double s=0.0;
  #pragma unroll
  for (int k=0;k<8;k++){ int j=k*256+tid; s += (double)row[j]*vb[j]; }
  s = wred_sumd(s);
  if((tid&63)==0) red[tid>>6]=s;
  __syncthreads();
  if (tid==0){
    double st = red[0]+red[1]+red[2]+red[3];
    double ui = u[b*NTOK+i];
    u[b*NTOK+i] = ui / (ui*st + EPSD);
  }
}

__global__ __launch_bounds__(256) void sink_col(const float* __restrict__ P,
    const double* __restrict__ u, double* __restrict__ R)
{
  __shared__ double ush[128];
  int cb = blockIdx.x, rb = blockIdx.y, b = blockIdx.z, tid = threadIdx.x;
  if (tid < 128) ush[tid] = u[b*NTOK + rb*128 + tid];
  __syncthreads();
  const float* Pp = P + ((long)b*NTOK + rb*128)*NTOK + cb*256 + tid;
  double acc=0.0;
  #pragma unroll 4
  for (int r=0;r<128;r++) acc += (double)Pp[(long)r*NTOK] * ush[r];
  atomicAdd(&R[b*NTOK + cb*256 + tid], acc);
}

__global__ void sink_v(double* __restrict__ v, const double* __restrict__ R){
  int idx = blockIdx.x*256+threadIdx.x;
  if (idx < BATCH*NTOK){ double vj=v[idx]; v[idx]=vj/(vj*R[idx]+EPSD); }
}

__global__ __launch_bounds__(256) void argmax_kernel(const float* __restrict__ P,
    const double* __restrict__ v, const int* __restrict__ perm,
    float* __restrict__ dout_perm)
{
  __shared__ double sv[4]; __shared__ int sj[4];
  int i = blockIdx.x, b = blockIdx.y, tid=threadIdx.x;
  const float* row = P + ((long)b*NTOK+i)*NTOK;
  const double* vb = v + b*NTOK;
  double bv=-1.0; int bj=0;
  #pragma unroll
  for (int k=0;k<8;k++){
    int j=k*256+tid; double val=(double)row[j]*vb[j];
    if (val>bv){bv=val;bj=j;}            // within-thread j ascending: first-max kept
  }
  for (int o=32;o;o>>=1){
    double ov=__shfl_xor(bv,o); int oj=__shfl_xor(bj,o);
    if (ov>bv || (ov==bv && oj<bj)){bv=ov;bj=oj;}
  }
  if ((tid&63)==0){ sv[tid>>6]=bv; sj[tid>>6]=bj; }
  __syncthreads();
  if (tid==0){
    for (int w=1;w<4;w++){
      if (sv[w]>bv || (sv[w]==bv && sj[w]<bj)){bv=sv[w];bj=sj[w];}
    }
    int np = perm[b*NTOK + bj];
    dout_perm[b*NTOK + i] = (float)np;
  }
}

__global__ void conv_kernel(const float* __restrict__ Of32, unsigned short* __restrict__ Ob){
  long n = (long)BATCH*NTOK*DMODEL;
  for (long i = (long)blockIdx.x*256 + threadIdx.x; i < n; i += (long)gridDim.x*256)
    Ob[i] = f2bf(Of32[i]);
}

__global__ __launch_bounds__(256) void out_kernel(
    const unsigned short* __restrict__ Ob, const unsigned short* __restrict__ Wob,
    const float* __restrict__ bo, float* __restrict__ dout)
{
  __shared__ unsigned short lds[(128+128)*32];
  int m0 = blockIdx.x*128, n0 = blockIdx.y*128;
  f32x4 acc[4][4];
  f32x4 z = {0.f,0.f,0.f,0.f};
  for (int i=0;i<4;i++) for(int j=0;j<4;j++) acc[i][j] = z;
  gemm_bt_core<128,128>(Ob + (long)m0*DMODEL, DMODEL, Wob + (long)n0*DMODEL, DMODEL,
                        DMODEL, acc, lds, lds + 128*32);
  int lane = threadIdx.x & 63, wave = threadIdx.x >> 6;
  int wm = wave>>1, wn = wave&1;
  int cr = (lane>>4)<<2, cc = lane & 15;
  for (int i=0;i<4;i++) for(int j=0;j<4;j++) for(int r=0;r<4;r++){
    int row = m0 + wm*64 + i*16 + cr + r;
    int col = n0 + wn*64 + j*16 + cc;
    dout[(long)row*DMODEL + col] = acc[i][j][r] + bo[col];
  }
}

__global__ void cert_kernel(const float* __restrict__ cert,
    const float* __restrict__ ctemp, const float* __restrict__ entsum,
    float* __restrict__ dout_cert)
{
  int idx = blockIdx.x*256+threadIdx.x;
  if (idx >= BATCH*NTOK) return;
  float ent = -entsum[idx] * (1.0f/16.0f);
  float ct = ctemp[0];
  float arg = ct * (logf((float)NTOK) - ent);
  float upd = 1.0f/(1.0f+expf(-arg));
  float c = fmaxf(cert[idx], upd);
  dout_cert[idx] = c;
}

extern "C" void kernel_launch(void* const* d_in, const int* in_sizes, int n_in,
                              void* d_out, int out_size, void* d_ws, size_t ws_size,
                              hipStream_t stream)
{
  const float* x    = (const float*)d_in[0];
  const float* cert = (const float*)d_in[1];
  const int*   perm = (const int*)d_in[2];
  const float* Wq   = (const float*)d_in[3];
  const float* bq   = (const float*)d_in[4];
  const float* Wk   = (const float*)d_in[5];
  const float* bk   = (const float*)d_in[6];
  const float* Wv   = (const float*)d_in[7];
  const float* bv   = (const float*)d_in[8];
  const float* Wo   = (const float*)d_in[9];
  const float* bo   = (const float*)d_in[10];
  const float* psc  = (const float*)d_in[11];
  const float* ctmp = (const float*)d_in[12];
  float* dout = (float*)d_out;

  // workspace layout (bf16 region, then f32, then f64)
  unsigned short* xb  = (unsigned short*)d_ws;          // 4,194,304
  unsigned short* Wqb = xb  + 4194304;                  // 1,048,576 each
  unsigned short* Wkb = Wqb + 1048576;
  unsigned short* Wvb = Wkb + 1048576;
  unsigned short* Wob = Wvb + 1048576;
  unsigned short* Qb  = Wob + 1048576;                  // 4,194,304 each
  unsigned short* Kb  = Qb  + 4194304;
  unsigned short* Vb  = Kb  + 4194304;
  unsigned short* Vt  = Vb  + 4194304;
  unsigned short* Abuf= Vt  + 4194304;                  // 8,388,608
  unsigned short* Ob  = Abuf;                           // reuse after last av
  float* S    = (float*)(Abuf + 8388608);               // 8,388,608 f32
  float* P0   = S    + 8388608;                         // 8,388,608 (zeroed; avg then P)
  float* Of32 = P0   + 8388608;                         // 4,194,304 (zeroed)
  float* ent  = Of32 + 4194304;                         // 4,096 (zeroed)
  double* u   = (double*)(ent + 4096);                  // 4,096 (init 1)
  double* v   = u + 4096;                               // 4,096 (init 1)
  double* R   = v + 4096;                               // 40,960 (zeroed)

  // input conversion f32 -> bf16
  f2b_kernel<<<dim3(16384),256,0,stream>>>(x,  xb,  4194304);
  f2b_kernel<<<dim3(4096), 256,0,stream>>>(Wq, Wqb, 1048576);
  f2b_kernel<<<dim3(4096), 256,0,stream>>>(Wk, Wkb, 1048576);
  f2b_kernel<<<dim3(4096), 256,0,stream>>>(Wv, Wvb, 1048576);
  f2b_kernel<<<dim3(4096), 256,0,stream>>>(Wo, Wob, 1048576);

  long nf = 12587008;                                   // P0 + Of32 + ent
  long ninit = nf + 8192 + 40960;
  init_kernel<<<dim3((unsigned)((ninit+255)/256)),256,0,stream>>>(P0, nf, u);

  qkv_kernel<<<dim3(32,24),256,0,stream>>>(xb, Wqb,bq, Wkb,bk, Wvb,bv, Qb,Kb,Vb);
  vtrans_kernel<<<dim3(64,32,2), dim3(32,8),0,stream>>>(Vb, Vt);

  for (int h=0; h<NHEADS; h++){
    scores_kernel <<<dim3(16,16,2),256,0,stream>>>(Qb, Kb, perm, psc, S, h);
    softmax_kernel<<<dim3(2048,2), 256,0,stream>>>(S, Abuf, P0, ent);
    av_kernel     <<<dim3(16,8,2), 256,0,stream>>>(Abuf, Vt, Of32, h);
  }

  pow_kernel<<<dim3(8192),256,0,stream>>>(P0, (long)2*2048*2048);
  for (int it=0; it<10; it++){
    sink_row<<<dim3(2048,2),256,0,stream>>>(P0, v, u);
    sink_col<<<dim3(8,16,2),256,0,stream>>>(P0, u, R + it*4096);
    sink_v  <<<dim3(16),   256,0,stream>>>(v, R + it*4096);
  }
  argmax_kernel<<<dim3(2048,2),256,0,stream>>>(P0, v, perm, dout + 4194304 + 4096);

  conv_kernel<<<dim3(4096),256,0,stream>>>(Of32, Ob);
  out_kernel <<<dim3(32,8),256,0,stream>>>(Ob, Wob, bo, dout);
  cert_kernel<<<dim3(16), 256,0,stream>>>(cert, ctmp, ent, dout + 4194304);
}

// Round 3
// 786.229 us; speedup vs baseline: 1.3627x; 1.3627x over previous
//
#include <hip/hip_runtime.h>
#include <cstdint>

#define NTOK 2048
#define DMODEL 1024
#define NHEADS 16
#define HD 64
#define BATCH 2
#define EPSF 1e-10f
#define EPSD 1e-10

typedef __attribute__((ext_vector_type(8))) short bf16x8;
typedef __attribute__((ext_vector_type(4))) float f32x4;

__device__ __forceinline__ unsigned short f2bf(float f){
  union { float f; unsigned int u; } c; c.f = f;
  unsigned int u = c.u;
  unsigned int r = (u + 0x7FFFu + ((u >> 16) & 1u)) >> 16;
  return (unsigned short)r;
}

__device__ __forceinline__ void async16(const unsigned short* g, unsigned short* lds_base){
  __builtin_amdgcn_global_load_lds((const __attribute__((address_space(1))) unsigned int*)g,
                                   (__attribute__((address_space(3))) unsigned int*)lds_base,
                                   16, 0, 0);
}

// C[m,n] = sum_k A[m,k] * B[n,k]  (both K-major bf16), 256 threads, waves 2x2.
template<int BM, int BN>
__device__ __forceinline__ void gemm_bt_core(
    const unsigned short* A, int lda,
    const unsigned short* B, int ldb,
    int K,
    f32x4 (&acc)[BM/32][BN/32],
    unsigned short* ldsA, unsigned short* ldsB)
{
  constexpr int TM = BM/32, TN = BN/32;
  const int tid  = threadIdx.x;
  const int lane = tid & 63;
  const int wave = tid >> 6;
  const int wm = wave >> 1, wn = wave & 1;
  const int fr = lane & 15;
  const int fk = (lane >> 4) << 3;
  const int sr = lane >> 2;
  const int sk = (lane & 3) << 3;

  for (int k0 = 0; k0 < K; k0 += 32){
    #pragma unroll
    for (int c = 0; c < BM/64; c++){
      int ch = c*4 + wave;
      async16(A + (long)(ch*16 + sr)*lda + (k0 + sk), ldsA + ch*512);
    }
    #pragma unroll
    for (int c = 0; c < BN/64; c++){
      int ch = c*4 + wave;
      async16(B + (long)(ch*16 + sr)*ldb + (k0 + sk), ldsB + ch*512);
    }
    __syncthreads();
    bf16x8 af[TM], bf[TN];
    #pragma unroll
    for (int i=0;i<TM;i++)
      af[i] = *(const bf16x8*)(ldsA + ((wm*TM*16) + i*16 + fr)*32 + fk);
    #pragma unroll
    for (int j=0;j<TN;j++)
      bf[j] = *(const bf16x8*)(ldsB + ((wn*TN*16) + j*16 + fr)*32 + fk);
    #pragma unroll
    for (int i=0;i<TM;i++)
      #pragma unroll
      for (int j=0;j<TN;j++)
        acc[i][j] = __builtin_amdgcn_mfma_f32_16x16x32_bf16(af[i], bf[j], acc[i][j], 0, 0, 0);
    __syncthreads();
  }
}

__device__ __forceinline__ double wred_sumd(double x){
  for(int o=32;o;o>>=1) x+=__shfl_xor(x,o); return x;
}

// ---------------- kernels ----------------

__global__ void f2b_kernel(const float* __restrict__ in, unsigned short* __restrict__ out, int n){
  int i = blockIdx.x*256 + threadIdx.x;
  if (i < n) out[i] = f2bf(in[i]);
}

__global__ void init_kernel(float* __restrict__ fz, long nf, double* __restrict__ dz){
  long idx = (long)blockIdx.x*256 + threadIdx.x;
  if (idx < nf) fz[idx] = 0.0f;
  else {
    long d = idx - nf;
    if (d < 8192) dz[d] = 1.0;                 // u, v
    else if (d < 8192 + 40960) dz[d] = 0.0;    // R
  }
}

__global__ __launch_bounds__(256) void qkv_kernel(
    const unsigned short* __restrict__ xb,
    const unsigned short* __restrict__ Wqb, const float* __restrict__ bq,
    const unsigned short* __restrict__ Wkb, const float* __restrict__ bk,
    const unsigned short* __restrict__ Wvb, const float* __restrict__ bv,
    unsigned short* __restrict__ Qb, unsigned short* __restrict__ Kb,
    unsigned short* __restrict__ Vb)
{
  __shared__ unsigned short lds[(128+128)*32];
  int sel = blockIdx.y >> 3;
  int n0 = (blockIdx.y & 7) * 128;
  int m0 = blockIdx.x * 128;
  const unsigned short* W = sel==0 ? Wqb : (sel==1 ? Wkb : Wvb);
  const float* bias       = sel==0 ? bq  : (sel==1 ? bk  : bv);
  unsigned short* out     = sel==0 ? Qb  : (sel==1 ? Kb  : Vb);
  f32x4 acc[4][4];
  f32x4 z = {0.f,0.f,0.f,0.f};
  for (int i=0;i<4;i++) for(int j=0;j<4;j++) acc[i][j] = z;
  gemm_bt_core<128,128>(xb + (long)m0*DMODEL, DMODEL, W + (long)n0*DMODEL, DMODEL,
                        DMODEL, acc, lds, lds + 128*32);
  int lane = threadIdx.x & 63, wave = threadIdx.x >> 6;
  int wm = wave>>1, wn = wave&1;
  int cr = (lane>>4)<<2, cc = lane & 15;
  for (int i=0;i<4;i++) for(int j=0;j<4;j++) for(int r=0;r<4;r++){
    int row = m0 + wm*64 + i*16 + cr + r;
    int col = n0 + wn*64 + j*16 + cc;
    out[(long)row*DMODEL + col] = f2bf(acc[i][j][r] + bias[col]);
  }
}

__global__ void vtrans_kernel(const unsigned short* __restrict__ Vb,
                              unsigned short* __restrict__ Vt)
{
  __shared__ unsigned short t[32][33];
  int b = blockIdx.z, i0 = blockIdx.x*32, e0 = blockIdx.y*32;
  int tx = threadIdx.x, ty = threadIdx.y;
  for (int r=0;r<32;r+=8) t[ty+r][tx] = Vb[((long)b*NTOK + i0+ty+r)*DMODEL + e0+tx];
  __syncthreads();
  for (int r=0;r<32;r+=8) Vt[((long)b*DMODEL + e0+ty+r)*NTOK + i0+tx] = t[tx][ty+r];
}

// ---- fused flash attention: per (b,h,row-block). Writes O (bf16, (b,n,d) layout),
// m/invl per row, entropy via per-row atomics. No S / Abuf materialization. ----
__global__ __launch_bounds__(256,2) void attnA_kernel(
    const unsigned short* __restrict__ Qb, const unsigned short* __restrict__ Kb,
    const unsigned short* __restrict__ Vt, const int* __restrict__ perm,
    const float* __restrict__ psc,
    unsigned short* __restrict__ Ob, float* __restrict__ mbuf,
    float* __restrict__ ilbuf, float* __restrict__ ent)
{
  __shared__ unsigned short Kt[2*128*32];   // [kc][row][32]
  __shared__ unsigned short Vtl[64*136];    // [col][128+pad]
  __shared__ unsigned short Pt[128*136];    // [row][128+pad]
  __shared__ int pbs[2048];

  const int tid  = threadIdx.x;
  const int lane = tid & 63;
  const int wave = tid >> 6;              // 4 waves stacked on rows (32 each)
  const int fr   = lane & 15;
  const int fkg  = lane >> 4;
  const int fk   = fkg << 3;
  const int cr   = fkg << 2;
  const int m0   = blockIdx.x * 128;
  const int h    = blockIdx.y;
  const int b    = blockIdx.z;

  for (int i = tid; i < 2048; i += 256) pbs[i] = perm[b*NTOK + i];

  bf16x8 qf[2][2];
  #pragma unroll
  for (int i=0;i<2;i++)
    #pragma unroll
    for (int kc=0;kc<2;kc++)
      qf[i][kc] = *(const bf16x8*)(Qb + ((long)(b*NTOK + m0 + wave*32 + i*16 + fr))*DMODEL + h*HD + kc*32 + fk);

  const float asc = fabsf(psc[h]);
  __syncthreads();

  float prow[2][4];
  #pragma unroll
  for (int i=0;i<2;i++)
    #pragma unroll
    for (int r=0;r<4;r++)
      prow[i][r] = (float)pbs[m0 + wave*32 + i*16 + cr + r];

  float mrow[2][4], lrow[2][4];
  #pragma unroll
  for (int i=0;i<2;i++) for(int r=0;r<4;r++){ mrow[i][r] = -1e30f; lrow[i][r] = 0.f; }

  // ---------- pass 1: online m,l ----------
  for (int j=0;j<16;j++){
    #pragma unroll
    for (int c=0;c<4;c++){
      int q = wave*4 + c;
      int kc = q >> 3, rb = (q & 7) * 16;
      async16(Kb + ((long)(b*NTOK + j*128 + rb + (lane>>2)))*DMODEL + h*HD + kc*32 + ((lane&3)<<3),
              Kt + kc*4096 + rb*32);
    }
    __syncthreads();
    f32x4 sacc[2][8];
    f32x4 z = {0.f,0.f,0.f,0.f};
    #pragma unroll
    for (int i=0;i<2;i++) for (int jj=0;jj<8;jj++) sacc[i][jj]=z;
    #pragma unroll
    for (int kc=0;kc<2;kc++){
      bf16x8 bfr[8];
      #pragma unroll
      for (int jj=0;jj<8;jj++) bfr[jj] = *(const bf16x8*)(Kt + kc*4096 + (jj*16+fr)*32 + fk);
      #pragma unroll
      for (int i=0;i<2;i++)
        #pragma unroll
        for (int jj=0;jj<8;jj++)
          sacc[i][jj] = __builtin_amdgcn_mfma_f32_16x16x32_bf16(qf[i][kc], bfr[jj], sacc[i][jj],0,0,0);
    }
    __syncthreads();
    float pcol[8];
    #pragma unroll
    for (int jj=0;jj<8;jj++) pcol[jj] = (float)pbs[j*128 + jj*16 + fr];
    #pragma unroll
    for (int i=0;i<2;i++)
      #pragma unroll
      for (int r=0;r<4;r++){
        float sv[8];
        float tm = -1e30f;
        #pragma unroll
        for (int jj=0;jj<8;jj++){
          sv[jj] = sacc[i][jj][r]*0.125f - fabsf(prow[i][r]-pcol[jj])*asc;
          tm = fmaxf(tm, sv[jj]);
        }
        #pragma unroll
        for (int o=1;o<16;o<<=1) tm = fmaxf(tm, __shfl_xor(tm,o));
        float nm = fmaxf(mrow[i][r], tm);
        float ts = 0.f;
        #pragma unroll
        for (int jj=0;jj<8;jj++) ts += expf(sv[jj]-nm);
        #pragma unroll
        for (int o=1;o<16;o<<=1) ts += __shfl_xor(ts,o);
        lrow[i][r] = lrow[i][r]*expf(mrow[i][r]-nm) + ts;
        mrow[i][r] = nm;
      }
  }
  float il[2][4];
  #pragma unroll
  for (int i=0;i<2;i++) for (int r=0;r<4;r++) il[i][r] = 1.0f/lrow[i][r];
  if (fr == 0){
    #pragma unroll
    for (int i=0;i<2;i++) for (int r=0;r<4;r++){
      int row = m0 + wave*32 + i*16 + cr + r;
      mbuf [((long)(b*NHEADS+h))*NTOK + row] = mrow[i][r];
      ilbuf[((long)(b*NHEADS+h))*NTOK + row] = il[i][r];
    }
  }

  // ---------- pass 2: P (transient) -> O, entropy ----------
  f32x4 oacc[2][4];
  {
    f32x4 z = {0.f,0.f,0.f,0.f};
    for (int i=0;i<2;i++) for(int jj=0;jj<4;jj++) oacc[i][jj]=z;
  }
  float ep[2][4] = {{0.f,0.f,0.f,0.f},{0.f,0.f,0.f,0.f}};
  for (int j=0;j<16;j++){
    __syncthreads();             // protect Pt/Vtl/Kt from prev-iter reads
    #pragma unroll
    for (int c=0;c<4;c++){
      int q = wave*4 + c;
      int kc = q >> 3, rb = (q & 7) * 16;
      async16(Kb + ((long)(b*NTOK + j*128 + rb + (lane>>2)))*DMODEL + h*HD + kc*32 + ((lane&3)<<3),
              Kt + kc*4096 + rb*32);
    }
    {
      int c = tid>>2, sg = tid&3;
      const unsigned short* vg = Vt + ((long)(b*DMODEL + h*HD + c))*NTOK + j*128 + sg*32;
      unsigned short* vl = Vtl + c*136 + sg*32;
      #pragma unroll
      for (int s2=0;s2<4;s2++)
        *(bf16x8*)(vl + s2*8) = *(const bf16x8*)(vg + s2*8);
    }
    __syncthreads();
    f32x4 sacc[2][8];
    {
      f32x4 z = {0.f,0.f,0.f,0.f};
      for (int i=0;i<2;i++) for(int jj=0;jj<8;jj++) sacc[i][jj]=z;
    }
    #pragma unroll
    for (int kc=0;kc<2;kc++){
      bf16x8 bfr[8];
      #pragma unroll
      for (int jj=0;jj<8;jj++) bfr[jj] = *(const bf16x8*)(Kt + kc*4096 + (jj*16+fr)*32 + fk);
      #pragma unroll
      for (int i=0;i<2;i++)
        #pragma unroll
        for (int jj=0;jj<8;jj++)
          sacc[i][jj] = __builtin_amdgcn_mfma_f32_16x16x32_bf16(qf[i][kc], bfr[jj], sacc[i][jj],0,0,0);
    }
    float pcol[8];
    #pragma unroll
    for (int jj=0;jj<8;jj++) pcol[jj] = (float)pbs[j*128 + jj*16 + fr];
    #pragma unroll
    for (int i=0;i<2;i++)
      #pragma unroll
      for (int jj=0;jj<8;jj++)
        #pragma unroll
        for (int r=0;r<4;r++){
          float sv = sacc[i][jj][r]*0.125f - fabsf(prow[i][r]-pcol[jj])*asc;
          float a = expf(sv - mrow[i][r]) * il[i][r];
          ep[i][r] += a * logf(a + EPSF);
          Pt[(wave*32 + i*16 + cr + r)*136 + jj*16 + fr] = f2bf(a);
        }
    __syncthreads();
    #pragma unroll
    for (int kp=0;kp<4;kp++){
      bf16x8 paf[2], pbf[4];
      #pragma unroll
      for (int i=0;i<2;i++)   paf[i]  = *(const bf16x8*)(Pt  + (wave*32+i*16+fr)*136 + kp*32 + fk);
      #pragma unroll
      for (int jj=0;jj<4;jj++) pbf[jj] = *(const bf16x8*)(Vtl + (jj*16+fr)*136 + kp*32 + fk);
      #pragma unroll
      for (int i=0;i<2;i++)
        #pragma unroll
        for (int jj=0;jj<4;jj++)
          oacc[i][jj] = __builtin_amdgcn_mfma_f32_16x16x32_bf16(paf[i], pbf[jj], oacc[i][jj],0,0,0);
    }
  }
  #pragma unroll
  for (int i=0;i<2;i++)
    #pragma unroll
    for (int jj=0;jj<4;jj++)
      #pragma unroll
      for (int r=0;r<4;r++){
        int row = m0 + wave*32 + i*16 + cr + r;
        Ob[((long)(b*NTOK + row))*DMODEL + h*HD + jj*16 + fr] = f2bf(oacc[i][jj][r]);
      }
  #pragma unroll
  for (int i=0;i<2;i++)
    #pragma unroll
    for (int r=0;r<4;r++){
      float e = ep[i][r];
      #pragma unroll
      for (int o=1;o<16;o<<=1) e += __shfl_xor(e,o);
      if (fr==0) atomicAdd(&ent[b*NTOK + m0 + wave*32 + i*16 + cr + r], e);
    }
}

// ---- avg over heads: per (b,row-block,col-tile) exclusive tile, loops heads. ----
__global__ __launch_bounds__(256,2) void attnB_kernel(
    const unsigned short* __restrict__ Qb, const unsigned short* __restrict__ Kb,
    const int* __restrict__ perm, const float* __restrict__ psc,
    const float* __restrict__ mbuf, const float* __restrict__ ilbuf,
    float* __restrict__ avg)
{
  __shared__ unsigned short Kt[2*128*32];
  __shared__ int pbs[2048];

  const int tid  = threadIdx.x;
  const int lane = tid & 63;
  const int wave = tid >> 6;
  const int fr   = lane & 15;
  const int fkg  = lane >> 4;
  const int fk   = fkg << 3;
  const int cr   = fkg << 2;
  const int j    = blockIdx.x;
  const int m0   = blockIdx.y * 128;
  const int b    = blockIdx.z;

  for (int i = tid; i < 2048; i += 256) pbs[i] = perm[b*NTOK + i];
  __syncthreads();

  float prow[2][4];
  #pragma unroll
  for (int i=0;i<2;i++)
    #pragma unroll
    for (int r=0;r<4;r++)
      prow[i][r] = (float)pbs[m0 + wave*32 + i*16 + cr + r];
  float pcol[8];
  #pragma unroll
  for (int jj=0;jj<8;jj++) pcol[jj] = (float)pbs[j*128 + jj*16 + fr];

  f32x4 av[2][8];
  {
    f32x4 z = {0.f,0.f,0.f,0.f};
    for (int i=0;i<2;i++) for(int jj=0;jj<8;jj++) av[i][jj]=z;
  }

  for (int h=0; h<NHEADS; h++){
    __syncthreads();
    #pragma unroll
    for (int c=0;c<4;c++){
      int q = wave*4 + c;
      int kc = q >> 3, rb = (q & 7) * 16;
      async16(Kb + ((long)(b*NTOK + j*128 + rb + (lane>>2)))*DMODEL + h*HD + kc*32 + ((lane&3)<<3),
              Kt + kc*4096 + rb*32);
    }
    bf16x8 qf[2][2];
    #pragma unroll
    for (int i=0;i<2;i++)
      #pragma unroll
      for (int kc=0;kc<2;kc++)
        qf[i][kc] = *(const bf16x8*)(Qb + ((long)(b*NTOK + m0 + wave*32 + i*16 + fr))*DMODEL + h*HD + kc*32 + fk);
    float mv[2][4], iv[2][4];
    #pragma unroll
    for (int i=0;i<2;i++)
      #pragma unroll
      for (int r=0;r<4;r++){
        long off = ((long)(b*NHEADS+h))*NTOK + m0 + wave*32 + i*16 + cr + r;
        mv[i][r] = mbuf[off];
        iv[i][r] = ilbuf[off];
      }
    float asc = fabsf(psc[h]);
    __syncthreads();
    f32x4 sacc[2][8];
    {
      f32x4 z = {0.f,0.f,0.f,0.f};
      for (int i=0;i<2;i++) for(int jj=0;jj<8;jj++) sacc[i][jj]=z;
    }
    #pragma unroll
    for (int kc=0;kc<2;kc++){
      bf16x8 bfr[8];
      #pragma unroll
      for (int jj=0;jj<8;jj++) bfr[jj] = *(const bf16x8*)(Kt + kc*4096 + (jj*16+fr)*32 + fk);
      #pragma unroll
      for (int i=0;i<2;i++)
        #pragma unroll
        for (int jj=0;jj<8;jj++)
          sacc[i][jj] = __builtin_amdgcn_mfma_f32_16x16x32_bf16(qf[i][kc], bfr[jj], sacc[i][jj],0,0,0);
    }
    #pragma unroll
    for (int i=0;i<2;i++)
      #pragma unroll
      for (int jj=0;jj<8;jj++)
        #pragma unroll
        for (int r=0;r<4;r++){
          float sv = sacc[i][jj][r]*0.125f - fabsf(prow[i][r]-pcol[jj])*asc;
          av[i][jj][r] += expf(sv - mv[i][r]) * iv[i][r];
        }
  }
  #pragma unroll
  for (int i=0;i<2;i++)
    #pragma unroll
    for (int jj=0;jj<8;jj++)
      #pragma unroll
      for (int r=0;r<4;r++){
        int row = m0 + wave*32 + i*16 + cr + r;
        avg[((long)(b*NTOK + row))*NTOK + j*128 + jj*16 + fr] = av[i][jj][r]*0.0625f;
      }
}

__global__ void pow_kernel(float* __restrict__ avg, long n){
  long idx = (long)blockIdx.x*256 + threadIdx.x;
  for (long i = idx; i < n; i += (long)gridDim.x*256){
    float xv = avg[i];
    avg[i] = expf(logf(xv + EPSF) * 10.0f);
  }
}

__global__ __launch_bounds__(256) void sink_row(const float* __restrict__ P,
    const double* __restrict__ v, double* __restrict__ u)
{
  __shared__ double red[4];
  int i = blockIdx.x, b = blockIdx.y, tid = threadIdx.x;
  const float* row = P + ((long)b*NTOK+i)*NTOK;
  const double* vb = v + b*NTOK;
  double s=0.0;
  #pragma unroll
  for (int k=0;k<8;k++){ int j=k*256+tid; s += (double)row[j]*vb[j]; }
  s = wred_sumd(s);
  if((tid&63)==0) red[tid>>6]=s;
  __syncthreads();
  if (tid==0){
    double st = red[0]+red[1]+red[2]+red[3];
    double ui = u[b*NTOK+i];
    u[b*NTOK+i] = ui / (ui*st + EPSD);
  }
}

__global__ __launch_bounds__(256) void sink_col(const float* __restrict__ P,
    const double* __restrict__ u, double* __restrict__ R)
{
  __shared__ double ush[128];
  int cb = blockIdx.x, rb = blockIdx.y, b = blockIdx.z, tid = threadIdx.x;
  if (tid < 128) ush[tid] = u[b*NTOK + rb*128 + tid];
  __syncthreads();
  const float* Pp = P + ((long)b*NTOK + rb*128)*NTOK + cb*256 + tid;
  double acc=0.0;
  #pragma unroll 4
  for (int r=0;r<128;r++) acc += (double)Pp[(long)r*NTOK] * ush[r];
  atomicAdd(&R[b*NTOK + cb*256 + tid], acc);
}

__global__ void sink_v(double* __restrict__ v, const double* __restrict__ R){
  int idx = blockIdx.x*256+threadIdx.x;
  if (idx < BATCH*NTOK){ double vj=v[idx]; v[idx]=vj/(vj*R[idx]+EPSD); }
}

__global__ __launch_bounds__(256) void argmax_kernel(const float* __restrict__ P,
    const double* __restrict__ v, const int* __restrict__ perm,
    float* __restrict__ dout_perm)
{
  __shared__ double sv[4]; __shared__ int sj[4];
  int i = blockIdx.x, b = blockIdx.y, tid=threadIdx.x;
  const float* row = P + ((long)b*NTOK+i)*NTOK;
  const double* vb = v + b*NTOK;
  double bv=-1.0; int bj=0;
  #pragma unroll
  for (int k=0;k<8;k++){
    int j=k*256+tid; double val=(double)row[j]*vb[j];
    if (val>bv){bv=val;bj=j;}
  }
  for (int o=32;o;o>>=1){
    double ov=__shfl_xor(bv,o); int oj=__shfl_xor(bj,o);
    if (ov>bv || (ov==bv && oj<bj)){bv=ov;bj=oj;}
  }
  if ((tid&63)==0){ sv[tid>>6]=bv; sj[tid>>6]=bj; }
  __syncthreads();
  if (tid==0){
    for (int w=1;w<4;w++){
      if (sv[w]>bv || (sv[w]==bv && sj[w]<bj)){bv=sv[w];bj=sj[w];}
    }
    int np = perm[b*NTOK + bj];
    dout_perm[b*NTOK + i] = (float)np;
  }
}

__global__ __launch_bounds__(256) void out_kernel(
    const unsigned short* __restrict__ Ob, const unsigned short* __restrict__ Wob,
    const float* __restrict__ bo, float* __restrict__ dout)
{
  __shared__ unsigned short lds[(128+128)*32];
  int m0 = blockIdx.x*128, n0 = blockIdx.y*128;
  f32x4 acc[4][4];
  f32x4 z = {0.f,0.f,0.f,0.f};
  for (int i=0;i<4;i++) for(int j=0;j<4;j++) acc[i][j] = z;
  gemm_bt_core<128,128>(Ob + (long)m0*DMODEL, DMODEL, Wob + (long)n0*DMODEL, DMODEL,
                        DMODEL, acc, lds, lds + 128*32);
  int lane = threadIdx.x & 63, wave = threadIdx.x >> 6;
  int wm = wave>>1, wn = wave&1;
  int cr = (lane>>4)<<2, cc = lane & 15;
  for (int i=0;i<4;i++) for(int j=0;j<4;j++) for(int r=0;r<4;r++){
    int row = m0 + wm*64 + i*16 + cr + r;
    int col = n0 + wn*64 + j*16 + cc;
    dout[(long)row*DMODEL + col] = acc[i][j][r] + bo[col];
  }
}

__global__ void cert_kernel(const float* __restrict__ cert,
    const float* __restrict__ ctemp, const float* __restrict__ entsum,
    float* __restrict__ dout_cert)
{
  int idx = blockIdx.x*256+threadIdx.x;
  if (idx >= BATCH*NTOK) return;
  float ent = -entsum[idx] * (1.0f/16.0f);
  float ct = ctemp[0];
  float arg = ct * (logf((float)NTOK) - ent);
  float upd = 1.0f/(1.0f+expf(-arg));
  float c = fmaxf(cert[idx], upd);
  dout_cert[idx] = c;
}

extern "C" void kernel_launch(void* const* d_in, const int* in_sizes, int n_in,
                              void* d_out, int out_size, void* d_ws, size_t ws_size,
                              hipStream_t stream)
{
  const float* x    = (const float*)d_in[0];
  const float* cert = (const float*)d_in[1];
  const int*   perm = (const int*)d_in[2];
  const float* Wq   = (const float*)d_in[3];
  const float* bq   = (const float*)d_in[4];
  const float* Wk   = (const float*)d_in[5];
  const float* bk   = (const float*)d_in[6];
  const float* Wv   = (const float*)d_in[7];
  const float* bv   = (const float*)d_in[8];
  const float* Wo   = (const float*)d_in[9];
  const float* bo   = (const float*)d_in[10];
  const float* psc  = (const float*)d_in[11];
  const float* ctmp = (const float*)d_in[12];
  float* dout = (float*)d_out;

  // workspace layout: bf16 region, then f32, then f64
  unsigned short* xb  = (unsigned short*)d_ws;          // 4,194,304
  unsigned short* Wqb = xb  + 4194304;
  unsigned short* Wkb = Wqb + 1048576;
  unsigned short* Wvb = Wkb + 1048576;
  unsigned short* Wob = Wvb + 1048576;
  unsigned short* Qb  = Wob + 1048576;                  // 4,194,304 each
  unsigned short* Kb  = Qb  + 4194304;
  unsigned short* Vb  = Kb  + 4194304;
  unsigned short* Vt  = Vb  + 4194304;
  unsigned short* Ob  = Vt  + 4194304;                  // 4,194,304
  float* avg  = (float*)(Ob + 4194304);                 // 8,388,608 (written by attnB)
  float* mbuf = avg  + 8388608;                         // 65,536
  float* ilbuf= mbuf + 65536;                           // 65,536
  float* ent  = ilbuf+ 65536;                           // 4,096 (zeroed)
  double* u   = (double*)(ent + 4096);                  // 4,096 (init 1)
  double* v   = u + 4096;                               // 4,096 (init 1)
  double* R   = v + 4096;                               // 40,960 (zeroed)

  // input conversion f32 -> bf16
  f2b_kernel<<<dim3(16384),256,0,stream>>>(x,  xb,  4194304);
  f2b_kernel<<<dim3(4096), 256,0,stream>>>(Wq, Wqb, 1048576);
  f2b_kernel<<<dim3(4096), 256,0,stream>>>(Wk, Wkb, 1048576);
  f2b_kernel<<<dim3(4096), 256,0,stream>>>(Wv, Wvb, 1048576);
  f2b_kernel<<<dim3(4096), 256,0,stream>>>(Wo, Wob, 1048576);

  long nf = 4096;                                       // ent only
  long ninit = nf + 8192 + 40960;
  init_kernel<<<dim3((unsigned)((ninit+255)/256)),256,0,stream>>>(ent, nf, u);

  qkv_kernel<<<dim3(32,24),256,0,stream>>>(xb, Wqb,bq, Wkb,bk, Wvb,bv, Qb,Kb,Vb);
  vtrans_kernel<<<dim3(64,32,2), dim3(32,8),0,stream>>>(Vb, Vt);

  attnA_kernel<<<dim3(16,16,2),256,0,stream>>>(Qb, Kb, Vt, perm, psc, Ob, mbuf, ilbuf, ent);
  attnB_kernel<<<dim3(16,16,2),256,0,stream>>>(Qb, Kb, perm, psc, mbuf, ilbuf, avg);

  pow_kernel<<<dim3(8192),256,0,stream>>>(avg, (long)2*2048*2048);
  for (int it=0; it<10; it++){
    sink_row<<<dim3(2048,2),256,0,stream>>>(avg, v, u);
    sink_col<<<dim3(8,16,2),256,0,stream>>>(avg, u, R + it*4096);
    sink_v  <<<dim3(16),   256,0,stream>>>(v, R + it*4096);
  }
  argmax_kernel<<<dim3(2048,2),256,0,stream>>>(avg, v, perm, dout + 4194304 + 4096);

  out_kernel <<<dim3(32,8),256,0,stream>>>(Ob, Wob, bo, dout);
  cert_kernel<<<dim3(16), 256,0,stream>>>(cert, ctmp, ent, dout + 4194304);
}